// Round 14
// baseline (146.897 us; speedup 1.0000x reference)
//
#include <hip/hip_runtime.h>

#define N_    8
#define C_    256
#define H_    100
#define W_    152
#define HW_   (H_*W_)          // 15200
#define NHW_  (N_*HW_)
#define NT_   20
#define TEMP_ 0.5f
#define LN_EPS_ 1e-5f
#define PB_   ((HW_+255)/256)  // 60 (masks kernel)
#define NCHK_ 4                // ch groups of 64 (part layout)

// pass1 v12: segment-rotation. block=(input,n,64ch-group,4096px strip);
// 16 waves x 4ch; LDS strip accumulators; wave w owns segment (w+t)&15.
#define SEG_    256
#define NSEGR_  16
#define STRIP_  4096
#define NSTRIP_ 4              // ceil(15200/4096)
#define NB1_    (2*NCHK_*N_*NSTRIP_)   // 256 blocks
#define NP2_    (N_*C_)

// spatial decomposition: 16 segments of 950 px per n
#define PXS_  950
#define NSEGS_ 16

__device__ __forceinline__ float wred_sum(float v){
#pragma unroll
  for(int o=32;o;o>>=1) v += __shfl_xor(v,o,64);
  return v;
}
__device__ __forceinline__ float wred_max(float v){
#pragma unroll
  for(int o=32;o;o>>=1) v = fmaxf(v,__shfl_xor(v,o,64));
  return v;
}
__device__ float block_sum(float v, float* sm){
  v = wred_sum(v);
  int nw = (int)(blockDim.x>>6);
  __syncthreads();
  if((threadIdx.x&63)==0) sm[threadIdx.x>>6]=v;
  __syncthreads();
  float r=0.f;
  for(int i=0;i<nw;i++) r+=sm[i];
  return r;
}
__device__ float block_max(float v, float* sm){
  v = wred_max(v);
  int nw = (int)(blockDim.x>>6);
  __syncthreads();
  if((threadIdx.x&63)==0) sm[threadIdx.x>>6]=v;
  __syncthreads();
  float r=-3.4e38f;
  for(int i=0;i<nw;i++) r=fmaxf(r,sm[i]);
  return r;
}

// acc: 0 fg, 1 bg, 2 total_d2, 3 maskS, 4 maskC, 5 rela, 6..13 bgcnt[n]
__global__ void k_masks(const float* __restrict__ gt, const int* __restrict__ imh,
                        const int* __restrict__ imw,
                        float* __restrict__ mask_fg, float* __restrict__ acc){
  __shared__ float sm[16];
  int b = blockIdx.x;
  int n = b / PB_;
  int pp = (b % PB_)*256 + threadIdx.x;
  float sw = (float)W_ / (float)imw[0];
  float sh = (float)H_ / (float)imh[0];
  float fg = 0.f;
  bool valid = pp < HW_;
  if (valid){
    float hh = (float)(pp / W_);
    float ww = (float)(pp % W_);
#pragma unroll
    for(int t=0;t<NT_;t++){
      const float* bx = gt + ((size_t)(n*NT_)+t)*4;
      float wmin = floorf(bx[0]*sw);
      float hmin = floorf(bx[1]*sh);
      float wmax = ceilf (bx[2]*sw);
      float hmax = ceilf (bx[3]*sh);
      float area = 1.f/((hmax+1.f-hmin)*(wmax+1.f-wmin));
      bool in = (hh>=hmin)&&(hh<=hmax)&&(ww>=wmin)&&(ww<=wmax);
      fg = fmaxf(fg, in?area:0.f);
    }
    mask_fg[n*HW_+pp] = fg;
  }
  float bgf = (valid && fg<=0.f) ? 1.f : 0.f;
  float s = block_sum(bgf, sm);
  if(threadIdx.x==0) atomicAdd(&acc[6+n], s);
}

// Pass 1 v12: segment-rotation shared-LDS accumulation, long sequential runs.
__global__ void __launch_bounds__(1024) k_pass1(
    const float* __restrict__ S, const float* __restrict__ T,
    const float* __restrict__ ws_w, const float* __restrict__ wt_w,
    float* __restrict__ part){
  __shared__ float fa[STRIP_];   // 16 KB  per-pixel sum |x|
  __shared__ float ca[STRIP_];   // 16 KB  per-pixel sum w*x
  __shared__ float lw[64];
  int b = blockIdx.x;
  int strip = b & (NSTRIP_-1);
  int grp   = (b>>2) & (NCHK_-1);
  int n     = (b>>4) & 7;
  int which = b>>7;
  int tid = threadIdx.x, wv = tid>>6, ln = tid&63;
  const float* X = which ? T : S;
  const float* W = which ? wt_w : ws_w;
  if(tid < 64) lw[tid] = W[grp*64 + tid];
  for(int i=tid;i<STRIP_;i+=1024){ fa[i]=0.f; ca[i]=0.f; }
  int px0 = strip*STRIP_;
  int c0 = grp*64 + wv*4;
  const float* R0 = X + (size_t)(n*C_+c0+0)*HW_;
  const float* R1 = X + (size_t)(n*C_+c0+1)*HW_;
  const float* R2 = X + (size_t)(n*C_+c0+2)*HW_;
  const float* R3 = X + (size_t)(n*C_+c0+3)*HW_;
  __syncthreads();
  float w0=lw[wv*4+0], w1=lw[wv*4+1], w2=lw[wv*4+2], w3=lw[wv*4+3];
  for(int t=0;t<NSEGR_;++t){
    int seg = (wv + t) & (NSEGR_-1);
    int pl = seg*SEG_ + ln*4;          // local strip px
    int pg = px0 + pl;                 // global px
    if(pg < HW_){                      // HW_%4==0 -> whole float4 valid
      float4 a = *(const float4*)(R0 + pg);
      float4 bq= *(const float4*)(R1 + pg);
      float4 cq= *(const float4*)(R2 + pg);
      float4 dq= *(const float4*)(R3 + pg);
      float f0 = fabsf(a.x)+fabsf(bq.x)+fabsf(cq.x)+fabsf(dq.x);
      float f1 = fabsf(a.y)+fabsf(bq.y)+fabsf(cq.y)+fabsf(dq.y);
      float f2 = fabsf(a.z)+fabsf(bq.z)+fabsf(cq.z)+fabsf(dq.z);
      float f3 = fabsf(a.w)+fabsf(bq.w)+fabsf(cq.w)+fabsf(dq.w);
      float g0 = w0*a.x+w1*bq.x+w2*cq.x+w3*dq.x;
      float g1 = w0*a.y+w1*bq.y+w2*cq.y+w3*dq.y;
      float g2 = w0*a.z+w1*bq.z+w2*cq.z+w3*dq.z;
      float g3 = w0*a.w+w1*bq.w+w2*cq.w+w3*dq.w;
      float4* fp = (float4*)&fa[pl];
      float4 vf = *fp;
      vf.x+=f0; vf.y+=f1; vf.z+=f2; vf.w+=f3;
      *fp = vf;
      float4* cp = (float4*)&ca[pl];
      float4 vc = *cp;
      vc.x+=g0; vc.y+=g1; vc.z+=g2; vc.w+=g3;
      *cp = vc;
    }
    __syncthreads();                   // step rotation fence
  }
  int stripN = HW_ - px0; if(stripN > STRIP_) stripN = STRIP_;
  size_t off = (size_t)n*HW_ + px0;
  int qf = which;            // 0:fea_s 1:fea_t
  int qc = 2+which;          // 2:cmp_s 3:cmp_t
  float* df = part + (size_t)(qf*NCHK_+grp)*NHW_ + off;
  float* dc = part + (size_t)(qc*NCHK_+grp)*NHW_ + off;
  for(int i=tid;i<stripN/4;i+=1024){
    ((float4*)df)[i] = ((float4*)fa)[i];
    ((float4*)dc)[i] = ((float4*)ca)[i];
  }
}

// Spatial phase A: combine 4 chunk slices into slot 0 + per-segment max.
__global__ void __launch_bounds__(256) k_combA(float* __restrict__ part,
                                               float* __restrict__ mpart){
  __shared__ float sm[8];
  int b = blockIdx.x;
  int q = b>>7, n = (b>>4)&7, seg = b&15;
  int tid = threadIdx.x;
  size_t off = (size_t)n*HW_ + seg*PXS_;
  float*       p0 = part + (size_t)(q*NCHK_+0)*NHW_ + off;
  const float* p1 = part + (size_t)(q*NCHK_+1)*NHW_ + off;
  const float* p2 = part + (size_t)(q*NCHK_+2)*NHW_ + off;
  const float* p3 = part + (size_t)(q*NCHK_+3)*NHW_ + off;
  float mloc = -3.4e38f;
  for(int i=tid;i<PXS_;i+=256){
    float w = p0[i]+p1[i]+p2[i]+p3[i];
    p0[i]=w;
    mloc = fmaxf(mloc,w);
  }
  float m = block_max(mloc,sm);
  if(tid==0) mpart[(q*8+n)*NSEGS_+seg]=m;
}

// Spatial phase B: global max per (q,n).
__global__ void k_sp2(const float* __restrict__ mpart, float* __restrict__ macc){
  int t=threadIdx.x;
  if(t<32){
    float m=-3.4e38f;
    for(int s=0;s<NSEGS_;s++) m=fmaxf(m,mpart[t*NSEGS_+s]);
    macc[t]=m;
  }
}

// Spatial phase C: exp-sum partials.
__global__ void __launch_bounds__(256) k_sp3(const float* __restrict__ part,
                                             const float* __restrict__ macc,
                                             float* __restrict__ zpart){
  __shared__ float sm[8];
  int b = blockIdx.x;
  int q = b>>7, n = (b>>4)&7, seg = b&15;
  int tid = threadIdx.x;
  const float* p0 = part + (size_t)(q*NCHK_)*NHW_ + (size_t)n*HW_ + seg*PXS_;
  float m = macc[q*8+n];
  const float invf = 1.f/((float)C_*TEMP_);
  float z=0.f;
  for(int i=tid;i<PXS_;i+=256){
    float v = p0[i];
    z += (q<2)? expf((v-m)*invf) : expf(v-m);
  }
  z = block_sum(z,sm);
  if(tid==0) zpart[(q*8+n)*NSEGS_+seg]=z;
}

// Spatial phase D: normalize p in-place + |Ss-St| -> acc[3].
__global__ void __launch_bounds__(256) k_sp4(float* __restrict__ part,
                                             const float* __restrict__ macc,
                                             const float* __restrict__ zpart,
                                             float* __restrict__ acc){
  __shared__ float zz[4];
  __shared__ float sm[8];
  int b = blockIdx.x;
  int n = b>>4, seg = b&15;
  int tid = threadIdx.x;
  if(tid<4){
    float z=0.f;
    for(int s=0;s<NSEGS_;s++) z += zpart[(tid*8+n)*NSEGS_+s];
    zz[tid]=z;
  }
  __syncthreads();
  float m1=macc[0*8+n], m2=macc[1*8+n], m3=macc[2*8+n], m4=macc[3*8+n];
  float i1=(float)HW_/zz[0], i2=(float)HW_/zz[1], i3=1.f/zz[2], i4=1.f/zz[3];
  size_t off = (size_t)n*HW_ + seg*PXS_;
  const float* fs = part + (size_t)(0*NCHK_)*NHW_ + off;
  const float* ft = part + (size_t)(1*NCHK_)*NHW_ + off;
  float* cs = part + (size_t)(2*NCHK_)*NHW_ + off;
  float* ct = part + (size_t)(3*NCHK_)*NHW_ + off;
  const float invf = 1.f/((float)C_*TEMP_);
  float d=0.f;
  for(int i=tid;i<PXS_;i+=256){
    float Ss = expf((fs[i]-m1)*invf)*i1;
    float St = expf((ft[i]-m2)*invf)*i2;
    d += fabsf(Ss-St);
    cs[i] = expf(cs[i]-m3)*i3;
    ct[i] = expf(ct[i]-m4)*i4;
  }
  d = block_sum(d,sm);
  if(tid==0) atomicAdd(&acc[3], d);
}

// Pass 2: block per (n,c): ctx dots + channel sums + masked-d2 scalars.
__global__ void __launch_bounds__(256) k_pass2(
    const float* __restrict__ S, const float* __restrict__ T,
    const float* __restrict__ cmp_s, const float* __restrict__ cmp_t,
    const float* __restrict__ mask_fg, const float* __restrict__ acc,
    float* __restrict__ ctx_s, float* __restrict__ ctx_t,
    float* __restrict__ ch_s, float* __restrict__ ch_t,
    float* __restrict__ sum_d, float* __restrict__ pblk2){
  __shared__ float sm[16];
  int b=blockIdx.x;
  int n=b>>8, c=b&255;
  const float4* Sp = (const float4*)(S + (size_t)(n*C_+c)*HW_);
  const float4* Tp = (const float4*)(T + (size_t)(n*C_+c)*HW_);
  const float4* Pp = (const float4*)(cmp_s + (size_t)n*HW_);
  const float4* Qp = (const float4*)(cmp_t + (size_t)n*HW_);
  const float4* Mp = (const float4*)(mask_fg + (size_t)n*HW_);
  float bgc = acc[6+n];
  float ibg = (bgc>0.f)?(1.f/bgc):1.f;
  float ibg2 = ibg*ibg;
  float as=0.f, at=0.f, dd=0.f, xs=0.f, xt=0.f;
  float wfg=0.f, wbg=0.f, wd2=0.f;
  const int HWE = HW_/8;   // 1900
  for(int p=threadIdx.x;p<HWE;p+=256){
    float4 s0=Sp[p], s1=Sp[p+HWE];
    float4 t0=Tp[p], t1=Tp[p+HWE];
    float4 u0=Pp[p], u1=Pp[p+HWE];
    float4 v0=Qp[p], v1=Qp[p+HWE];
    float4 m0=Mp[p], m1=Mp[p+HWE];
    as += fabsf(s0.x)+fabsf(s0.y)+fabsf(s0.z)+fabsf(s0.w)
        + fabsf(s1.x)+fabsf(s1.y)+fabsf(s1.z)+fabsf(s1.w);
    at += fabsf(t0.x)+fabsf(t0.y)+fabsf(t0.z)+fabsf(t0.w)
        + fabsf(t1.x)+fabsf(t1.y)+fabsf(t1.z)+fabsf(t1.w);
    float d0x=s0.x-t0.x, d0y=s0.y-t0.y, d0z=s0.z-t0.z, d0w=s0.w-t0.w;
    float d1x=s1.x-t1.x, d1y=s1.y-t1.y, d1z=s1.z-t1.z, d1w=s1.w-t1.w;
    dd += d0x+d0y+d0z+d0w + d1x+d1y+d1z+d1w;
    float q0x=d0x*d0x, q0y=d0y*d0y, q0z=d0z*d0z, q0w=d0w*d0w;
    float q1x=d1x*d1x, q1y=d1y*d1y, q1z=d1z*d1z, q1w=d1w*d1w;
    wd2 += q0x+q0y+q0z+q0w + q1x+q1y+q1z+q1w;
    wfg += m0.x*m0.x*q0x + m0.y*m0.y*q0y + m0.z*m0.z*q0z + m0.w*m0.w*q0w
         + m1.x*m1.x*q1x + m1.y*m1.y*q1y + m1.z*m1.z*q1z + m1.w*m1.w*q1w;
    wbg += ((m0.x<=0.f)?ibg2:0.f)*q0x + ((m0.y<=0.f)?ibg2:0.f)*q0y
         + ((m0.z<=0.f)?ibg2:0.f)*q0z + ((m0.w<=0.f)?ibg2:0.f)*q0w
         + ((m1.x<=0.f)?ibg2:0.f)*q1x + ((m1.y<=0.f)?ibg2:0.f)*q1y
         + ((m1.z<=0.f)?ibg2:0.f)*q1z + ((m1.w<=0.f)?ibg2:0.f)*q1w;
    xs += s0.x*u0.x+s0.y*u0.y+s0.z*u0.z+s0.w*u0.w
        + s1.x*u1.x+s1.y*u1.y+s1.z*u1.z+s1.w*u1.w;
    xt += t0.x*v0.x+t0.y*v0.y+t0.z*v0.z+t0.w*v0.w
        + t1.x*v1.x+t1.y*v1.y+t1.z*v1.z+t1.w*v1.w;
  }
  as = block_sum(as,sm);
  at = block_sum(at,sm);
  dd = block_sum(dd,sm);
  xs = block_sum(xs,sm);
  xt = block_sum(xt,sm);
  wfg = block_sum(wfg,sm);
  wbg = block_sum(wbg,sm);
  wd2 = block_sum(wd2,sm);
  if(threadIdx.x==0){
    ch_s[n*C_+c]=as; ch_t[n*C_+c]=at; sum_d[n*C_+c]=dd;
    ctx_s[n*C_+c]=xs; ctx_t[n*C_+c]=xt;
    pblk2[0*NP2_+b]=wfg; pblk2[1*NP2_+b]=wbg; pblk2[2*NP2_+b]=wd2;
  }
}

// Reduce pass2 per-block scalar partials into acc[0..2]; block per quantity.
__global__ void k_scal2(const float* __restrict__ pblk2, float* __restrict__ acc){
  __shared__ float sm[4];
  int q = blockIdx.x, tid = threadIdx.x;
  float v=0.f;
  for(int i=tid;i<NP2_;i+=256) v += pblk2[q*NP2_+i];
  float s = block_sum(v, sm);
  if(tid==0) acc[q]=s;
}

// Transpose the 4 small weight matrices so the GC-block matvecs read coalesced.
__global__ void k_tw(const float* __restrict__ sw1, const float* __restrict__ tw1,
                     const float* __restrict__ sw2, const float* __restrict__ tw2,
                     float* __restrict__ o){
  int g = blockIdx.x;
  int which = g>>7;
  int i = (g&127)*256 + threadIdx.x;
  const float* src = (which==0)?sw1 : (which==1)?tw1 : (which==2)?sw2 : tw2;
  int Ccols = (which<2)?256:128;
  int Rrows = (which<2)?128:256;
  int r = i/Ccols, c = i%Ccols;
  o[which*32768 + c*Rrows + r] = src[i];
}

// Fused channel-softmax L1 + GC-block rela partial. Block per n.
__global__ void k_chcadd(const float* __restrict__ ch_s, const float* __restrict__ ch_t,
    const float* __restrict__ ctx_s, const float* __restrict__ ctx_t,
    const float* __restrict__ wT,
    const float* __restrict__ sb1, const float* __restrict__ slnw, const float* __restrict__ slnb,
    const float* __restrict__ sb2,
    const float* __restrict__ tb1, const float* __restrict__ tlnw, const float* __restrict__ tlnb,
    const float* __restrict__ tb2,
    const float* __restrict__ sum_d, float* __restrict__ acc){
  __shared__ float sm[16];
  __shared__ float sred[8];
  __shared__ float lcs[C_], lct[C_], lh[C_];
  int n=blockIdx.x, tid=threadIdx.x;
  {
    const float invc = 1.f/((float)HW_*TEMP_);
    float vs = ch_s[n*C_+tid]*invc;
    float vt = ch_t[n*C_+tid]*invc;
    float ms = block_max(vs,sm);
    float mt = block_max(vt,sm);
    float es = expf(vs-ms), et = expf(vt-mt);
    float zs = block_sum(es,sm), zt = block_sum(et,sm);
    float Cs = (float)C_*es/zs, Ct = (float)C_*et/zt;
    float d = block_sum(fabsf(Cs-Ct), sm);
    if(tid==0) atomicAdd(&acc[4], d);
  }
  const float* w1T_s = wT;
  const float* w1T_t = wT + 32768;
  const float* w2T_s = wT + 65536;
  const float* w2T_t = wT + 98304;
  lcs[tid]=ctx_s[n*C_+tid]; lct[tid]=ctx_t[n*C_+tid];
  __syncthreads();
  int half = tid>>7, k = tid&127;
  float y;
  {
    const float* w1T = half? w1T_t : w1T_s;
    const float* b1  = half? tb1 : sb1;
    const float* src = half? lct : lcs;
    float a = b1[k];
    for(int c=0;c<C_;c++) a += src[c]*w1T[c*128+k];
    y = a;
  }
  {
    int wv = tid>>6;
    float s1 = wred_sum(y);
    float s2 = wred_sum(y*y);
    __syncthreads();
    if((tid&63)==0){ sred[wv]=s1; sred[4+wv]=s2; }
    __syncthreads();
    int h2 = half<<1;
    float mu = (sred[h2]+sred[h2+1])*(1.f/128.f);
    float msq = (sred[4+h2]+sred[4+h2+1])*(1.f/128.f);
    float var = msq - mu*mu;
    const float* lnw = half? tlnw : slnw;
    const float* lnb = half? tlnb : slnb;
    float yv = (y-mu)/sqrtf(var+LN_EPS_)*lnw[k]+lnb[k];
    lh[tid] = fmaxf(yv, 0.f);
  }
  __syncthreads();
  {
    int c = tid;
    float os = sb2[c], ot = tb2[c];
    for(int kk=0;kk<128;kk++){
      os += lh[kk]*w2T_s[kk*256+c];
      ot += lh[128+kk]*w2T_t[kk*256+c];
    }
    float e = os - ot;
    float p = 2.f*e*sum_d[n*C_+c] + (float)HW_*e*e;
    float s = block_sum(p, sm);
    if(tid==0) atomicAdd(&acc[5], s);
  }
}

__global__ void k_final(const float* __restrict__ acc, float* __restrict__ out){
  if(threadIdx.x==0 && blockIdx.x==0){
    float fg=acc[0], bg=acc[1], d2=acc[2], mS=acc[3], mC=acc[4], rl=acc[5];
    const float invN = 1.f/(float)N_;
    out[0] = 0.001f*fg*invN + 0.0005f*bg*invN
           + 0.001f*(mC+mS)*invN + 5e-6f*(d2+rl)*invN;
  }
}

extern "C" void kernel_launch(void* const* d_in, const int* in_sizes, int n_in,
                              void* d_out, int out_size, void* d_ws, size_t ws_size,
                              hipStream_t stream){
  (void)in_sizes; (void)n_in; (void)out_size; (void)ws_size;
  const float* S     = (const float*)d_in[0];
  const float* T     = (const float*)d_in[1];
  const float* gt    = (const float*)d_in[2];
  const float* cms_w = (const float*)d_in[3];
  const float* cmt_w = (const float*)d_in[5];
  const float* cas_w1=(const float*)d_in[7],  *cas_b1=(const float*)d_in[8];
  const float* cas_lnw=(const float*)d_in[9], *cas_lnb=(const float*)d_in[10];
  const float* cas_w2=(const float*)d_in[11], *cas_b2=(const float*)d_in[12];
  const float* cat_w1=(const float*)d_in[13], *cat_b1=(const float*)d_in[14];
  const float* cat_lnw=(const float*)d_in[15],*cat_lnb=(const float*)d_in[16];
  const float* cat_w2=(const float*)d_in[17], *cat_b2=(const float*)d_in[18];
  const int* imh=(const int*)d_in[19];
  const int* imw=(const int*)d_in[20];

  float* ws = (float*)d_ws;
  const int NC = N_*C_;
  float* mask_fg = ws;                   // [NHW_]
  float* part    = mask_fg + NHW_;       // [16][NHW_] = 7.8 MB (L3-safe)
  float* pblk2   = part + (size_t)4*NCHK_*NHW_;  // [3*NP2_]
  float* ctx_s   = pblk2 + 3*NP2_;       // [NC]
  float* ctx_t   = ctx_s + NC;
  float* ch_s    = ctx_t + NC;
  float* ch_t    = ch_s + NC;
  float* sum_d   = ch_t + NC;
  float* wT      = sum_d + NC;           // [4*32768]
  float* acc     = wT + 4*32768;         // [16] zeroed
  float* mpart   = acc + 16;             // [512]
  float* zpart   = mpart + 512;          // [512]
  float* macc    = zpart + 512;          // [32]
  hipMemsetAsync(acc, 0, 16*sizeof(float), stream);

  float* cmp_s = part + (size_t)2*NCHK_*NHW_;  // combined slices (slot 0)
  float* cmp_t = part + (size_t)3*NCHK_*NHW_;

  k_tw    <<<512,        256, 0, stream>>>(cas_w1,cat_w1,cas_w2,cat_w2, wT);
  k_masks <<<N_*PB_,     256, 0, stream>>>(gt, imh, imw, mask_fg, acc);
  k_pass1 <<<NB1_,      1024, 0, stream>>>(S,T,cms_w,cmt_w, part);
  k_combA <<<512,        256, 0, stream>>>(part, mpart);
  k_sp2   <<<1,           64, 0, stream>>>(mpart, macc);
  k_sp3   <<<512,        256, 0, stream>>>(part, macc, zpart);
  k_sp4   <<<128,        256, 0, stream>>>(part, macc, zpart, acc);
  k_pass2 <<<NP2_,       256, 0, stream>>>(S,T,cmp_s,cmp_t, mask_fg, acc,
                                           ctx_s,ctx_t,ch_s,ch_t,sum_d, pblk2);
  k_scal2 <<<3,          256, 0, stream>>>(pblk2, acc);
  k_chcadd<<<N_,         256, 0, stream>>>(ch_s,ch_t, ctx_s,ctx_t, wT,
                                           cas_b1,cas_lnw,cas_lnb,cas_b2,
                                           cat_b1,cat_lnw,cat_lnb,cat_b2,
                                           sum_d,acc);
  k_final <<<1,           64, 0, stream>>>(acc,(float*)d_out);
}

// Round 15
// 134.099 us; speedup vs baseline: 1.0954x; 1.0954x over previous
//
#include <hip/hip_runtime.h>

#define N_    8
#define C_    256
#define H_    100
#define W_    152
#define HW_   (H_*W_)          // 15200
#define NHW_  (N_*HW_)
#define NT_   20
#define TEMP_ 0.5f
#define LN_EPS_ 1e-5f
#define PB_   ((HW_+255)/256)  // 60 (masks part of twmask)

// pass1 v11 (best measured): block = (n, 256-px strip, 128-ch half);
// 8 stages x 16 ch staged via async global_load_lds DMA.
#define NCHK_ 2                // channel halves
#define HALFC_ 128
#define STGC_ 16
#define NSTG_ 8
#define PXB1_ 256
#define NSTRP_ 60              // strips (tail overlaps)
#define NB1_  (N_*NSTRP_*NCHK_)      // 960 blocks
#define NP2_  (N_*C_)

// spatial decomposition: 16 segments of 950 px per n
#define PXS_  950
#define NSEGS_ 16

__device__ __forceinline__ void gload_lds16(const float* g, float* l){
  __builtin_amdgcn_global_load_lds(
      (const __attribute__((address_space(1))) void*)(g),
      (__attribute__((address_space(3))) void*)(l), 16, 0, 0);
}

__device__ __forceinline__ float wred_sum(float v){
#pragma unroll
  for(int o=32;o;o>>=1) v += __shfl_xor(v,o,64);
  return v;
}
__device__ __forceinline__ float wred_max(float v){
#pragma unroll
  for(int o=32;o;o>>=1) v = fmaxf(v,__shfl_xor(v,o,64));
  return v;
}
__device__ float block_sum(float v, float* sm){
  v = wred_sum(v);
  int nw = (int)(blockDim.x>>6);
  __syncthreads();
  if((threadIdx.x&63)==0) sm[threadIdx.x>>6]=v;
  __syncthreads();
  float r=0.f;
  for(int i=0;i<nw;i++) r+=sm[i];
  return r;
}
__device__ float block_max(float v, float* sm){
  v = wred_max(v);
  int nw = (int)(blockDim.x>>6);
  __syncthreads();
  if((threadIdx.x&63)==0) sm[threadIdx.x>>6]=v;
  __syncthreads();
  float r=-3.4e38f;
  for(int i=0;i<nw;i++) r=fmaxf(r,sm[i]);
  return r;
}

// acc: 3 maskS, 4 maskC, 5 rela, 6..13 bgcnt[n]  (0..2 unused now)
// Fused: blocks 0..511 transpose weights; blocks 512..991 compute masks.
__global__ void k_twmask(const float* __restrict__ sw1, const float* __restrict__ tw1,
                         const float* __restrict__ sw2, const float* __restrict__ tw2,
                         float* __restrict__ o,
                         const float* __restrict__ gt, const int* __restrict__ imh,
                         const int* __restrict__ imw,
                         float* __restrict__ mask_fg, float* __restrict__ acc){
  __shared__ float sm[16];
  int b = blockIdx.x;
  if(b < 512){
    int which = b>>7;
    int i = (b&127)*256 + threadIdx.x;
    const float* src = (which==0)?sw1 : (which==1)?tw1 : (which==2)?sw2 : tw2;
    int Ccols = (which<2)?256:128;
    int Rrows = (which<2)?128:256;
    int r = i/Ccols, c = i%Ccols;
    o[which*32768 + c*Rrows + r] = src[i];
    return;
  }
  int bm = b - 512;
  int n = bm / PB_;
  int pp = (bm % PB_)*256 + threadIdx.x;
  float sw = (float)W_ / (float)imw[0];
  float sh = (float)H_ / (float)imh[0];
  float fg = 0.f;
  bool valid = pp < HW_;
  if (valid){
    float hh = (float)(pp / W_);
    float ww = (float)(pp % W_);
#pragma unroll
    for(int t=0;t<NT_;t++){
      const float* bx = gt + ((size_t)(n*NT_)+t)*4;
      float wmin = floorf(bx[0]*sw);
      float hmin = floorf(bx[1]*sh);
      float wmax = ceilf (bx[2]*sw);
      float hmax = ceilf (bx[3]*sh);
      float area = 1.f/((hmax+1.f-hmin)*(wmax+1.f-wmin));
      bool in = (hh>=hmin)&&(hh<=hmax)&&(ww>=wmin)&&(ww<=wmax);
      fg = fmaxf(fg, in?area:0.f);
    }
    mask_fg[n*HW_+pp] = fg;
  }
  float bgf = (valid && fg<=0.f) ? 1.f : 0.f;
  float s = block_sum(bgf, sm);
  if(threadIdx.x==0) atomicAdd(&acc[6+n], s);
}

// Pass 1 v11: async-DMA staging + pixel-owner LDS consume.
__global__ void __launch_bounds__(256) k_pass1(
    const float* __restrict__ S, const float* __restrict__ T,
    const float* __restrict__ ws_w, const float* __restrict__ wt_w,
    const float* __restrict__ mask_fg,
    float* __restrict__ part, float* __restrict__ pblk,
    const float* __restrict__ acc){
  __shared__ float s16[STGC_][PXB1_];   // 16 KB
  __shared__ float t16[STGC_][PXB1_];   // 16 KB
  __shared__ float m2fg[PXB1_], m2bg[PXB1_];
  __shared__ float lw_s[HALFC_], lw_t[HALFC_];
  __shared__ float sm[8];
  int b = blockIdx.x;
  int half = b & 1;
  int sg = (b>>1) % NSTRP_;
  int n  = b/(NCHK_*NSTRP_);
  int tid = threadIdx.x, wv = tid>>6, ln = tid&63;
  int c0h = half*HALFC_;
  int pv0 = sg*PXB1_;                 // scalar-valid start
  int px0 = pv0;
  if(px0 + PXB1_ > HW_) px0 = HW_ - PXB1_;   // overlap tail (in-bounds)
  size_t base = (size_t)n*HW_ + px0;
  if(tid < HALFC_){ lw_s[tid]=ws_w[c0h+tid]; lw_t[tid]=wt_w[c0h+tid]; }
  {
    float bgc = acc[6+n];
    float ibg = (bgc>0.f)?(1.f/bgc):1.f;
    if(tid < PXB1_){
      float m = mask_fg[base+tid];
      m2fg[tid] = m*m;
      m2bg[tid] = (m<=0.f)? ibg*ibg : 0.f;
    }
  }
  __syncthreads();
  float fs=0.f, ft=0.f, cs=0.f, ct=0.f, d2=0.f;
  for(int st=0; st<NSTG_; ++st){
#pragma unroll
    for(int r=0;r<4;++r){
      int row = wv*4+r;
      int c = c0h + st*STGC_ + row;
      const float* gS = S + (size_t)(n*C_+c)*HW_ + px0 + ln*4;
      const float* gT = T + (size_t)(n*C_+c)*HW_ + px0 + ln*4;
      gload_lds16(gS, &s16[row][0]);
      gload_lds16(gT, &t16[row][0]);
    }
    __syncthreads();                   // drains vmcnt (DMA complete)
#pragma unroll
    for(int c=0;c<STGC_;++c){
      float sv = s16[c][tid];
      float tv = t16[c][tid];
      int ci = st*STGC_+c;
      fs += fabsf(sv); ft += fabsf(tv);
      cs += lw_s[ci]*sv; ct += lw_t[ci]*tv;
      float d = sv-tv;  d2 += d*d;
    }
    __syncthreads();                   // WAR before next stage overwrite
  }
  part[(size_t)(0*NCHK_+half)*NHW_ + base + tid] = fs;
  part[(size_t)(1*NCHK_+half)*NHW_ + base + tid] = ft;
  part[(size_t)(2*NCHK_+half)*NHW_ + base + tid] = cs;
  part[(size_t)(3*NCHK_+half)*NHW_ + base + tid] = ct;
  bool sval = (px0 + tid) >= pv0;     // exclude overlapped tail pixels
  float wd2 = sval? d2 : 0.f;
  float wfg = sval? m2fg[tid]*d2 : 0.f;
  float wbg = sval? m2bg[tid]*d2 : 0.f;
  float s1 = block_sum(wfg, sm);
  float s2 = block_sum(wbg, sm);
  float s3 = block_sum(wd2, sm);
  if(tid==0){
    pblk[0*NB1_+b]=s1; pblk[1*NB1_+b]=s2; pblk[2*NB1_+b]=s3;
  }
}

// Spatial phase A: combine NCHK_ slices into slot 0 + per-segment max.
__global__ void __launch_bounds__(256) k_combA(float* __restrict__ part,
                                               float* __restrict__ mpart){
  __shared__ float sm[8];
  int b = blockIdx.x;
  int q = b>>7, n = (b>>4)&7, seg = b&15;
  int tid = threadIdx.x;
  size_t off = (size_t)n*HW_ + seg*PXS_;
  float* p0 = part + (size_t)(q*NCHK_+0)*NHW_ + off;
  float mloc = -3.4e38f;
  for(int i=tid;i<PXS_;i+=256){
    float w = p0[i];
#pragma unroll
    for(int c=1;c<NCHK_;c++) w += (part + (size_t)(q*NCHK_+c)*NHW_ + off)[i];
    p0[i]=w;
    mloc = fmaxf(mloc,w);
  }
  float m = block_max(mloc,sm);
  if(tid==0) mpart[(q*8+n)*NSEGS_+seg]=m;
}

// Spatial phase C: exp-sum partials (global max re-derived from mpart inline).
__global__ void __launch_bounds__(256) k_sp3(const float* __restrict__ part,
                                             const float* __restrict__ mpart,
                                             float* __restrict__ zpart){
  __shared__ float sm[8];
  int b = blockIdx.x;
  int q = b>>7, n = (b>>4)&7, seg = b&15;
  int tid = threadIdx.x;
  const float* p0 = part + (size_t)(q*NCHK_)*NHW_ + (size_t)n*HW_ + seg*PXS_;
  float m = -3.4e38f;
#pragma unroll
  for(int s=0;s<NSEGS_;s++) m = fmaxf(m, mpart[(q*8+n)*NSEGS_+s]);
  const float invf = 1.f/((float)C_*TEMP_);
  float z=0.f;
  for(int i=tid;i<PXS_;i+=256){
    float v = p0[i];
    z += (q<2)? expf((v-m)*invf) : expf(v-m);
  }
  z = block_sum(z,sm);
  if(tid==0) zpart[(q*8+n)*NSEGS_+seg]=z;
}

// Spatial phase D: normalize p in-place + |Ss-St| -> acc[3].
__global__ void __launch_bounds__(256) k_sp4(float* __restrict__ part,
                                             const float* __restrict__ mpart,
                                             const float* __restrict__ zpart,
                                             float* __restrict__ acc){
  __shared__ float zz[4];
  __shared__ float mm[4];
  __shared__ float sm[8];
  int b = blockIdx.x;
  int n = b>>4, seg = b&15;
  int tid = threadIdx.x;
  if(tid<4){
    float z=0.f, m=-3.4e38f;
    for(int s=0;s<NSEGS_;s++){
      z += zpart[(tid*8+n)*NSEGS_+s];
      m = fmaxf(m, mpart[(tid*8+n)*NSEGS_+s]);
    }
    zz[tid]=z; mm[tid]=m;
  }
  __syncthreads();
  float m1=mm[0], m2=mm[1], m3=mm[2], m4=mm[3];
  float i1=(float)HW_/zz[0], i2=(float)HW_/zz[1], i3=1.f/zz[2], i4=1.f/zz[3];
  size_t off = (size_t)n*HW_ + seg*PXS_;
  const float* fs = part + (size_t)(0*NCHK_)*NHW_ + off;
  const float* ft = part + (size_t)(1*NCHK_)*NHW_ + off;
  float* cs = part + (size_t)(2*NCHK_)*NHW_ + off;
  float* ct = part + (size_t)(3*NCHK_)*NHW_ + off;
  const float invf = 1.f/((float)C_*TEMP_);
  float d=0.f;
  for(int i=tid;i<PXS_;i+=256){
    float Ss = expf((fs[i]-m1)*invf)*i1;
    float St = expf((ft[i]-m2)*invf)*i2;
    d += fabsf(Ss-St);
    cs[i] = expf(cs[i]-m3)*i3;
    ct[i] = expf(ct[i]-m4)*i4;
  }
  d = block_sum(d,sm);
  if(tid==0) atomicAdd(&acc[3], d);
}

// Pass 2: block per (n,c): ctx dots + linear channel sums; 2 float4/stream/iter.
__global__ void __launch_bounds__(256) k_pass2(
    const float* __restrict__ S, const float* __restrict__ T,
    const float* __restrict__ cmp_s, const float* __restrict__ cmp_t,
    float* __restrict__ ctx_s, float* __restrict__ ctx_t,
    float* __restrict__ ch_s, float* __restrict__ ch_t,
    float* __restrict__ sum_d){
  __shared__ float sm[16];
  int b=blockIdx.x;
  int n=b>>8, c=b&255;
  const float4* Sp = (const float4*)(S + (size_t)(n*C_+c)*HW_);
  const float4* Tp = (const float4*)(T + (size_t)(n*C_+c)*HW_);
  const float4* Pp = (const float4*)(cmp_s + (size_t)n*HW_);
  const float4* Qp = (const float4*)(cmp_t + (size_t)n*HW_);
  float as=0.f, at=0.f, dd=0.f, xs=0.f, xt=0.f;
  const int HWE = HW_/8;   // 1900
  for(int p=threadIdx.x;p<HWE;p+=256){
    float4 s0=Sp[p], s1=Sp[p+HWE];
    float4 t0=Tp[p], t1=Tp[p+HWE];
    float4 u0=Pp[p], u1=Pp[p+HWE];
    float4 v0=Qp[p], v1=Qp[p+HWE];
    as += fabsf(s0.x)+fabsf(s0.y)+fabsf(s0.z)+fabsf(s0.w)
        + fabsf(s1.x)+fabsf(s1.y)+fabsf(s1.z)+fabsf(s1.w);
    at += fabsf(t0.x)+fabsf(t0.y)+fabsf(t0.z)+fabsf(t0.w)
        + fabsf(t1.x)+fabsf(t1.y)+fabsf(t1.z)+fabsf(t1.w);
    dd += (s0.x-t0.x)+(s0.y-t0.y)+(s0.z-t0.z)+(s0.w-t0.w)
        + (s1.x-t1.x)+(s1.y-t1.y)+(s1.z-t1.z)+(s1.w-t1.w);
    xs += s0.x*u0.x+s0.y*u0.y+s0.z*u0.z+s0.w*u0.w
        + s1.x*u1.x+s1.y*u1.y+s1.z*u1.z+s1.w*u1.w;
    xt += t0.x*v0.x+t0.y*v0.y+t0.z*v0.z+t0.w*v0.w
        + t1.x*v1.x+t1.y*v1.y+t1.z*v1.z+t1.w*v1.w;
  }
  as = block_sum(as,sm);
  at = block_sum(at,sm);
  dd = block_sum(dd,sm);
  xs = block_sum(xs,sm);
  xt = block_sum(xt,sm);
  if(threadIdx.x==0){
    ch_s[n*C_+c]=as; ch_t[n*C_+c]=at; sum_d[n*C_+c]=dd;
    ctx_s[n*C_+c]=xs; ctx_t[n*C_+c]=xt;
  }
}

// Fused channel-softmax L1 + GC-block rela partial. Block per n.
__global__ void k_chcadd(const float* __restrict__ ch_s, const float* __restrict__ ch_t,
    const float* __restrict__ ctx_s, const float* __restrict__ ctx_t,
    const float* __restrict__ wT,
    const float* __restrict__ sb1, const float* __restrict__ slnw, const float* __restrict__ slnb,
    const float* __restrict__ sb2,
    const float* __restrict__ tb1, const float* __restrict__ tlnw, const float* __restrict__ tlnb,
    const float* __restrict__ tb2,
    const float* __restrict__ sum_d, float* __restrict__ acc){
  __shared__ float sm[16];
  __shared__ float sred[8];
  __shared__ float lcs[C_], lct[C_], lh[C_];
  int n=blockIdx.x, tid=threadIdx.x;
  {
    const float invc = 1.f/((float)HW_*TEMP_);
    float vs = ch_s[n*C_+tid]*invc;
    float vt = ch_t[n*C_+tid]*invc;
    float ms = block_max(vs,sm);
    float mt = block_max(vt,sm);
    float es = expf(vs-ms), et = expf(vt-mt);
    float zs = block_sum(es,sm), zt = block_sum(et,sm);
    float Cs = (float)C_*es/zs, Ct = (float)C_*et/zt;
    float d = block_sum(fabsf(Cs-Ct), sm);
    if(tid==0) atomicAdd(&acc[4], d);
  }
  const float* w1T_s = wT;
  const float* w1T_t = wT + 32768;
  const float* w2T_s = wT + 65536;
  const float* w2T_t = wT + 98304;
  lcs[tid]=ctx_s[n*C_+tid]; lct[tid]=ctx_t[n*C_+tid];
  __syncthreads();
  int half = tid>>7, k = tid&127;
  float y;
  {
    const float* w1T = half? w1T_t : w1T_s;
    const float* b1  = half? tb1 : sb1;
    const float* src = half? lct : lcs;
    float a = b1[k];
    for(int c=0;c<C_;c++) a += src[c]*w1T[c*128+k];
    y = a;
  }
  {
    int wv = tid>>6;
    float s1 = wred_sum(y);
    float s2 = wred_sum(y*y);
    __syncthreads();
    if((tid&63)==0){ sred[wv]=s1; sred[4+wv]=s2; }
    __syncthreads();
    int h2 = half<<1;
    float mu = (sred[h2]+sred[h2+1])*(1.f/128.f);
    float msq = (sred[4+h2]+sred[4+h2+1])*(1.f/128.f);
    float var = msq - mu*mu;
    const float* lnw = half? tlnw : slnw;
    const float* lnb = half? tlnb : slnb;
    float yv = (y-mu)/sqrtf(var+LN_EPS_)*lnw[k]+lnb[k];
    lh[tid] = fmaxf(yv, 0.f);
  }
  __syncthreads();
  {
    int c = tid;
    float os = sb2[c], ot = tb2[c];
    for(int kk=0;kk<128;kk++){
      os += lh[kk]*w2T_s[kk*256+c];
      ot += lh[128+kk]*w2T_t[kk*256+c];
    }
    float e = os - ot;
    float p = 2.f*e*sum_d[n*C_+c] + (float)HW_*e*e;
    float s = block_sum(p, sm);
    if(tid==0) atomicAdd(&acc[5], s);
  }
}

// Final: reduce pass1 scalar partials + combine all loss terms.
__global__ void k_final(const float* __restrict__ pblk,
                        const float* __restrict__ acc, float* __restrict__ out){
  __shared__ float sm[4];
  int tid = threadIdx.x;
  float v[3];
  for(int q=0;q<3;q++){
    float s=0.f;
    for(int i=tid;i<NB1_;i+=256) s += pblk[q*NB1_+i];
    v[q] = block_sum(s, sm);
  }
  if(tid==0){
    float fg=v[0], bg=v[1], d2=v[2], mS=acc[3], mC=acc[4], rl=acc[5];
    const float invN = 1.f/(float)N_;
    out[0] = 0.001f*fg*invN + 0.0005f*bg*invN
           + 0.001f*(mC+mS)*invN + 5e-6f*(d2+rl)*invN;
  }
}

extern "C" void kernel_launch(void* const* d_in, const int* in_sizes, int n_in,
                              void* d_out, int out_size, void* d_ws, size_t ws_size,
                              hipStream_t stream){
  (void)in_sizes; (void)n_in; (void)out_size; (void)ws_size;
  const float* S     = (const float*)d_in[0];
  const float* T     = (const float*)d_in[1];
  const float* gt    = (const float*)d_in[2];
  const float* cms_w = (const float*)d_in[3];
  const float* cmt_w = (const float*)d_in[5];
  const float* cas_w1=(const float*)d_in[7],  *cas_b1=(const float*)d_in[8];
  const float* cas_lnw=(const float*)d_in[9], *cas_lnb=(const float*)d_in[10];
  const float* cas_w2=(const float*)d_in[11], *cas_b2=(const float*)d_in[12];
  const float* cat_w1=(const float*)d_in[13], *cat_b1=(const float*)d_in[14];
  const float* cat_lnw=(const float*)d_in[15],*cat_lnb=(const float*)d_in[16];
  const float* cat_w2=(const float*)d_in[17], *cat_b2=(const float*)d_in[18];
  const int* imh=(const int*)d_in[19];
  const int* imw=(const int*)d_in[20];

  float* ws = (float*)d_ws;
  const int NC = N_*C_;
  float* mask_fg = ws;                   // [NHW_]
  float* part    = mask_fg + NHW_;       // [4*NCHK_][NHW_] = 3.9 MB (L3-safe)
  float* pblk    = part + (size_t)4*NCHK_*NHW_;  // [3*NB1_]
  float* ctx_s   = pblk + 3*NB1_;        // [NC]
  float* ctx_t   = ctx_s + NC;
  float* ch_s    = ctx_t + NC;
  float* ch_t    = ch_s + NC;
  float* sum_d   = ch_t + NC;
  float* wT      = sum_d + NC;           // [4*32768]
  float* acc     = wT + 4*32768;         // [16] zeroed
  float* mpart   = acc + 16;             // [512]
  float* zpart   = mpart + 512;          // [512]
  hipMemsetAsync(acc, 0, 16*sizeof(float), stream);

  float* cmp_s = part + (size_t)2*NCHK_*NHW_;  // combined slices (slot 0)
  float* cmp_t = part + (size_t)3*NCHK_*NHW_;

  k_twmask<<<992,        256, 0, stream>>>(cas_w1,cat_w1,cas_w2,cat_w2, wT,
                                           gt, imh, imw, mask_fg, acc);
  k_pass1 <<<NB1_,       256, 0, stream>>>(S,T,cms_w,cmt_w,mask_fg, part, pblk, acc);
  k_combA <<<512,        256, 0, stream>>>(part, mpart);
  k_sp3   <<<512,        256, 0, stream>>>(part, mpart, zpart);
  k_sp4   <<<128,        256, 0, stream>>>(part, mpart, zpart, acc);
  k_pass2 <<<NP2_,       256, 0, stream>>>(S,T,cmp_s,cmp_t,
                                           ctx_s,ctx_t,ch_s,ch_t,sum_d);
  k_chcadd<<<N_,         256, 0, stream>>>(ch_s,ch_t, ctx_s,ctx_t, wT,
                                           cas_b1,cas_lnw,cas_lnb,cas_b2,
                                           cat_b1,cat_lnw,cat_lnb,cat_b2,
                                           sum_d,acc);
  k_final <<<1,          256, 0, stream>>>(pblk, acc, (float*)d_out);
}